// Round 3
// baseline (1913.562 us; speedup 1.0000x reference)
//
#include <hip/hip_runtime.h>
#include <hip/hip_bf16.h>
#include <math.h>
#include <stddef.h>

// Problem constants
#define Bc 4
#define Nc 1024
#define Mc 2048
#define Dc 768
#define Hc 6
#define HDc 128
#define Lc 3
#define Vc 4096
#define FFc 3072

typedef short bf16x8 __attribute__((ext_vector_type(8)));
typedef float f32x4 __attribute__((ext_vector_type(4)));
typedef ushort usx4 __attribute__((ext_vector_type(4)));

__device__ __forceinline__ float gelu_tanh(float x) {
    float x3 = x * x * x;
    return 0.5f * x * (1.0f + tanhf(0.7978845608028654f * (x + 0.044715f * x3)));
}
__device__ __forceinline__ float silu_f(float x) {
    return x / (1.0f + expf(-x));
}
// fp32 -> bf16 RNE, bit-level
__device__ __forceinline__ ushort f2bf(float x) {
    unsigned u = __float_as_uint(x);
    unsigned r = (u + 0x7fffu + ((u >> 16) & 1u)) >> 16;
    return (ushort)r;
}
__device__ __forceinline__ float bf2f(ushort u) {
    return __uint_as_float(((unsigned)u) << 16);
}
// async global->LDS 16B per lane; LDS dst = base + lane*16 (wave-uniform base)
__device__ __forceinline__ void gl2lds16(const ushort* g, ushort* l) {
    __builtin_amdgcn_global_load_lds(
        (const __attribute__((address_space(1))) unsigned int*)(g),
        (__attribute__((address_space(3))) unsigned int*)(l),
        16, 0, 0);
}

// ---------------------------------------------------------------------------
// Fourier positional encoding
// ---------------------------------------------------------------------------
__global__ __launch_bounds__(256) void pos_pe_kernel(
    const float* __restrict__ freq, const float* __restrict__ pe_w,
    const float* __restrict__ pe_b, float* __restrict__ pos)
{
    int n = blockIdx.x;
    __shared__ float feat[64];
    int tid = threadIdx.x;
    if (tid < 64) {
        float f;
        if (tid < 32) f = cosf((float)n * freq[tid]);
        else          f = sinf((float)n * freq[tid - 32]);
        feat[tid] = f * 0.125f;
    }
    __syncthreads();
    for (int d = tid; d < Dc; d += 256) {
        float s = pe_b[d];
#pragma unroll
        for (int h = 0; h < 64; ++h) s += feat[h] * pe_w[h * Dc + d];
        pos[(size_t)n * Dc + d] = s;
    }
}

__global__ __launch_bounds__(256) void embed_kernel(
    const int* __restrict__ tokens, const float* __restrict__ embed_w,
    const float* __restrict__ pos, float* __restrict__ x)
{
    size_t idx = (size_t)blockIdx.x * 256 + threadIdx.x;
    if (idx >= (size_t)Bc * Nc * Dc) return;
    int d  = (int)(idx % Dc);
    size_t bn = idx / Dc;
    int n  = (int)(bn % Nc);
    int tok = tokens[bn];
    x[idx] = embed_w[(size_t)tok * Dc + d] + pos[(size_t)n * Dc + d];
}

__global__ __launch_bounds__(64) void dpb_kernel(
    const float* __restrict__ w0, const float* __restrict__ b0,
    const float* __restrict__ w1, const float* __restrict__ b1,
    const float* __restrict__ w2, const float* __restrict__ b2,
    float* __restrict__ table)
{
    int r = blockIdx.x;
    int j = threadIdx.x;
    float dist = (float)r - (float)(Nc - 1);
    __shared__ float s0[64], s1[64];
    s0[j] = silu_f(dist * w0[j] + b0[j]);
    __syncthreads();
    float a = b1[j];
#pragma unroll 8
    for (int k = 0; k < 64; ++k) a += s0[k] * w1[k * 64 + j];
    s1[j] = silu_f(a);
    __syncthreads();
    if (j < Hc) {
        float t = b2[j];
#pragma unroll 8
        for (int k = 0; k < 64; ++k) t += s1[k] * w2[k * Hc + j];
        table[(size_t)r * Hc + j] = t;
    }
}

// RMSNorm fp32 in -> bf16 out. Dc=768=192*4: threads 0..191 do float4 lanes.
__global__ __launch_bounds__(256) void rms_kernel(
    const float* __restrict__ in, const float* __restrict__ w,
    ushort* __restrict__ out)
{
    size_t row = blockIdx.x;
    const float* rp = in + row * Dc;
    ushort* op = out + row * Dc;
    int tid = threadIdx.x;
    float4 v = make_float4(0.f, 0.f, 0.f, 0.f);
    float s = 0.f;
    int d4 = tid << 2;
    if (tid < 192) {
        v = *(const float4*)&rp[d4];
        s = v.x * v.x + v.y * v.y + v.z * v.z + v.w * v.w;
    }
    __shared__ float red[256];
    red[tid] = s;
    __syncthreads();
    for (int o = 128; o > 0; o >>= 1) {
        if (tid < o) red[tid] += red[tid + o];
        __syncthreads();
    }
    float rs = rsqrtf(red[0] * (1.0f / Dc) + 1e-8f);
    if (tid < 192) {
        float4 wv = *(const float4*)&w[d4];
        usx4 pk;
        pk.x = f2bf(v.x * rs * wv.x); pk.y = f2bf(v.y * rs * wv.y);
        pk.z = f2bf(v.z * rs * wv.z); pk.w = f2bf(v.w * rs * wv.w);
        *(usx4*)&op[d4] = pk;
    }
}

// ---------------------------------------------------------------------------
// Fused split-K reduce + residual update + RMSNorm:
//   x[row] += sum_z P[z][row];  out[row] = rms(x[row]) (bf16)
// Dc = 768 = 192*4; threads 0..191 each own one float4.
// ---------------------------------------------------------------------------
__global__ __launch_bounds__(256) void rms_reduce_kernel(
    float* __restrict__ x, const float* __restrict__ P, int nsplit, size_t MN,
    const float* __restrict__ w, ushort* __restrict__ out)
{
    size_t row = blockIdx.x;
    float* xp = x + row * Dc;
    ushort* op = out + row * Dc;
    int tid = threadIdx.x;
    int d4 = tid << 2;
    float4 v = make_float4(0.f, 0.f, 0.f, 0.f);
    float s = 0.f;
    if (tid < 192) {
        v = *(const float4*)&xp[d4];
        for (int z = 0; z < nsplit; ++z) {
            float4 p = *(const float4*)&P[(size_t)z * MN + row * Dc + d4];
            v.x += p.x; v.y += p.y; v.z += p.z; v.w += p.w;
        }
        *(float4*)&xp[d4] = v;
        s = v.x * v.x + v.y * v.y + v.z * v.z + v.w * v.w;
    }
    __shared__ float red[256];
    red[tid] = s;
    __syncthreads();
    for (int o = 128; o > 0; o >>= 1) {
        if (tid < o) red[tid] += red[tid + o];
        __syncthreads();
    }
    float rs = rsqrtf(red[0] * (1.0f / Dc) + 1e-8f);
    if (tid < 192) {
        float4 wv = *(const float4*)&w[d4];
        usx4 pk;
        pk.x = f2bf(v.x * rs * wv.x); pk.y = f2bf(v.y * rs * wv.y);
        pk.z = f2bf(v.z * rs * wv.z); pk.w = f2bf(v.w * rs * wv.w);
        *(usx4*)&op[d4] = pk;
    }
}

// ---------------------------------------------------------------------------
// Weight transpose+convert: in fp32 [K][N] -> out bf16 [N][K]. 64x64 tiles.
// ---------------------------------------------------------------------------
__global__ __launch_bounds__(256) void wt_kernel(
    const float* __restrict__ in, ushort* __restrict__ out, int K_, int N_)
{
    int n0 = blockIdx.x << 6, k0 = blockIdx.y << 6;
    __shared__ ushort t[64][65];
    int tid = threadIdx.x;
    int r = tid >> 4, c4 = (tid & 15) << 2;
    for (int rr = r; rr < 64; rr += 16) {
        float4 v = *(const float4*)&in[(size_t)(k0 + rr) * N_ + n0 + c4];
        t[rr][c4]     = f2bf(v.x);
        t[rr][c4 + 1] = f2bf(v.y);
        t[rr][c4 + 2] = f2bf(v.z);
        t[rr][c4 + 3] = f2bf(v.w);
    }
    __syncthreads();
    int nr = tid >> 2, cw = (tid & 3) << 4;
    ushort tmp[16];
#pragma unroll
    for (int j = 0; j < 16; ++j) tmp[j] = t[cw + j][nr];
#pragma unroll
    for (int s = 0; s < 2; ++s)
        *(bf16x8*)&out[(size_t)(n0 + nr) * K_ + k0 + cw + (s << 3)] =
            *(const bf16x8*)&tmp[s << 3];
}

// ---------------------------------------------------------------------------
// bf16 MFMA GEMM: C[M,N] = epi(A[M,K] @ Bt[N,K]^T)
// 128x128 tile, BK=32, 4 waves (2x2 of 64x64), frag-order LDS via
// global_load_lds (lane-linear dst, conflict-free).
// Double-buffered LDS, prefetch next K-step before compute, ONE
// __syncthreads per K-step. Split-K over blockIdx.z stores fp32 partial
// tiles to Cf + z*M*N. Epilogue stages the output tile through LDS
// (two 64x128 fp32 halves, reusing the K-loop buffers) so ALL global
// stores are coalesced 16B/lane vector stores (f32x4 or bf16x8).
// ---------------------------------------------------------------------------
__global__ __launch_bounds__(256) void gemm_bf16_kernel(
    const ushort* __restrict__ A, const ushort* __restrict__ Bt,
    const float* __restrict__ bias, const float* __restrict__ res,
    float* __restrict__ Cf, ushort* __restrict__ Cb,
    int M_, int N_, int K_, int act, int ksplit)
{
    __shared__ __align__(16) ushort sraw[2 * 2 * 8 * 512];   // 32 KB total
    ushort* As = sraw;                 // [2][8*512]
    ushort* Bs = sraw + 2 * 8 * 512;   // [2][8*512]
    int m0 = blockIdx.y << 7, n0 = blockIdx.x << 7;
    int tid = threadIdx.x;
    int wave = tid >> 6, lane = tid & 63;
    int li = lane & 15, lq = lane >> 4;
    int wm = (wave >> 1) << 6, wn = (wave & 1) << 6;

    int kchunk = K_ / ksplit;           // callers guarantee K_ % (32*ksplit)==0
    int kbeg = blockIdx.z * kchunk;
    int niter = kchunk >> 5;

    f32x4 acc[4][4];
#pragma unroll
    for (int i = 0; i < 4; ++i)
#pragma unroll
        for (int j = 0; j < 4; ++j) {
            acc[i][j][0] = 0.f; acc[i][j][1] = 0.f;
            acc[i][j][2] = 0.f; acc[i][j][3] = 0.f;
        }

    auto stage = [&](int buf, int k0) {
#pragma unroll
        for (int i = 0; i < 2; ++i) {
            int fb = (wave << 1) + i;   // 0..7: rows fb*16..fb*16+15
            const ushort* ga = A  + (size_t)(m0 + (fb << 4) + li) * K_ + k0 + (lq << 3);
            const ushort* gb = Bt + (size_t)(n0 + (fb << 4) + li) * K_ + k0 + (lq << 3);
            gl2lds16(ga, &As[(buf << 12) + (fb << 9)]);
            gl2lds16(gb, &Bs[(buf << 12) + (fb << 9)]);
        }
    };

    stage(0, kbeg);
    __syncthreads();   // drains prologue loads (vmcnt 0)

    for (int it = 0; it < niter; ++it) {
        int cur = it & 1;
        if (it + 1 < niter) stage(cur ^ 1, kbeg + ((it + 1) << 5));
        bf16x8 af[4], bfr[4];
#pragma unroll
        for (int t = 0; t < 4; ++t) {
            af[t]  = *(const bf16x8*)&As[(cur << 12) + (((wm >> 4) + t) << 9) + (lane << 3)];
            bfr[t] = *(const bf16x8*)&Bs[(cur << 12) + (((wn >> 4) + t) << 9) + (lane << 3)];
        }
#pragma unroll
        for (int mt = 0; mt < 4; ++mt)
#pragma unroll
            for (int nt = 0; nt < 4; ++nt)
                acc[mt][nt] = __builtin_amdgcn_mfma_f32_16x16x32_bf16(
                    af[mt], bfr[nt], acc[mt][nt], 0, 0, 0);
        __syncthreads();   // prefetch landed; LDS reads of cur complete
    }

    // ---- epilogue: stage tile through LDS, coalesced vector stores ----
    float* lt = (float*)sraw;   // 64 rows x 128 cols fp32 = 32 KB
    float* dstF = Cf;
    if (ksplit > 1) dstF = Cf + (size_t)blockIdx.z * M_ * N_;

#pragma unroll
    for (int half = 0; half < 2; ++half) {
        __syncthreads();
        if ((wm >> 6) == half) {
#pragma unroll
            for (int mt = 0; mt < 4; ++mt) {
#pragma unroll
                for (int r = 0; r < 4; ++r) {
                    int lrow = (mt << 4) + (lq << 2) + r;   // 0..63
                    int grow = m0 + (half << 6) + lrow;
#pragma unroll
                    for (int nt = 0; nt < 4; ++nt) {
                        int col = wn + (nt << 4) + li;
                        float v = acc[mt][nt][r];
                        if (ksplit == 1) {
                            int gcol = n0 + col;
                            if (bias) v += bias[gcol];
                            if (act == 1) v = gelu_tanh(v);
                            if (res) v += res[(size_t)grow * N_ + gcol];
                        }
                        lt[(lrow << 7) + col] = v;
                    }
                }
            }
        }
        __syncthreads();
        if (Cb) {
            // 4 passes x 16 rows; lane covers 8 cols -> 16B bf16 store
            int lrow = tid >> 4;            // 0..15
            int c8 = (tid & 15) << 3;       // 0..120
#pragma unroll
            for (int p = 0; p < 4; ++p) {
                int row = (p << 4) + lrow;
                f32x4 a = *(const f32x4*)&lt[(row << 7) + c8];
                f32x4 b = *(const f32x4*)&lt[(row << 7) + c8 + 4];
                union { bf16x8 v; ushort u[8]; } pk;
#pragma unroll
                for (int j = 0; j < 4; ++j) {
                    pk.u[j] = f2bf(a[j]);
                    pk.u[4 + j] = f2bf(b[j]);
                }
                int grow = m0 + (half << 6) + row;
                *(bf16x8*)&Cb[(size_t)grow * N_ + n0 + c8] = pk.v;
            }
        } else {
            // 8 passes x 8 rows; lane covers 4 cols -> 16B fp32 store
            int lrow = tid >> 5;            // 0..7
            int c4 = (tid & 31) << 2;       // 0..124
#pragma unroll
            for (int p = 0; p < 8; ++p) {
                int row = (p << 3) + lrow;
                f32x4 a = *(const f32x4*)&lt[(row << 7) + c4];
                int grow = m0 + (half << 6) + row;
                *(f32x4*)&dstF[(size_t)grow * N_ + n0 + c4] = a;
            }
        }
    }
}

// ---------------------------------------------------------------------------
// Unpack SA qkv (bf16) -> bf16 q,k (l2-normalized), v [BH][N][128]
// ---------------------------------------------------------------------------
__global__ __launch_bounds__(128) void unpack_sa_kernel(
    const ushort* __restrict__ qkv, ushort* __restrict__ qo,
    ushort* __restrict__ ko, ushort* __restrict__ vo)
{
    int bid = blockIdx.x;
    int h = bid % Hc;
    int bn = bid / Hc;
    int b = bn / Nc, n = bn % Nc;
    int d = threadIdx.x;
    size_t base = (size_t)bn * (3 * Hc * HDc) + (size_t)(h * HDc + d) * 3;
    float q = bf2f(qkv[base]), k = bf2f(qkv[base + 1]);
    ushort v = qkv[base + 2];
    __shared__ float rq[128], rk[128];
    rq[d] = q * q; rk[d] = k * k;
    __syncthreads();
    for (int o = 64; o > 0; o >>= 1) {
        if (d < o) { rq[d] += rq[d + o]; rk[d] += rk[d + o]; }
        __syncthreads();
    }
    float qn = fmaxf(sqrtf(rq[0]), 1e-12f);
    float kn = fmaxf(sqrtf(rk[0]), 1e-12f);
    size_t oidx = (((size_t)(b * Hc + h) * Nc) + n) * HDc + d;
    qo[oidx] = f2bf(q / qn);
    ko[oidx] = f2bf(k / kn);
    vo[oidx] = v;
}

// ---------------------------------------------------------------------------
// Unpack CA q from 2 fp32 split-K partials: sum -> bf16 [BH][N][128]
// ---------------------------------------------------------------------------
__global__ __launch_bounds__(256) void unpack_caq_red_kernel(
    const float* __restrict__ P, ushort* __restrict__ qo)
{
    size_t idx = (size_t)blockIdx.x * 256 + threadIdx.x;
    if (idx >= (size_t)Bc * Hc * Nc * HDc) return;
    int d = (int)(idx & (HDc - 1));
    size_t t = idx >> 7;
    int n = (int)(t % Nc); t /= Nc;
    int h = (int)(t % Hc); int b = (int)(t / Hc);
    const size_t MNq = (size_t)Bc * Nc * (Hc * HDc);
    size_t src = ((size_t)(b * Nc + n)) * (Hc * HDc) + h * HDc + d;
    qo[idx] = f2bf(P[src] + P[MNq + src]);
}

// ---------------------------------------------------------------------------
// Unpack CA kv: bf16 [B*M][(h*128+d)*2+c] -> bf16 k,v [BH][M][128]
// ---------------------------------------------------------------------------
__global__ __launch_bounds__(256) void unpack_cakv_kernel(
    const ushort* __restrict__ in, ushort* __restrict__ ko, ushort* __restrict__ vo)
{
    size_t idx = (size_t)blockIdx.x * 256 + threadIdx.x;
    if (idx >= (size_t)Bc * Hc * Mc * HDc) return;
    int d = (int)(idx & (HDc - 1));
    size_t t = idx >> 7;
    int m = (int)(t % Mc); t /= Mc;
    int h = (int)(t % Hc); int b = (int)(t / Hc);
    size_t src = ((size_t)(b * Mc + m)) * (2 * Hc * HDc) + (size_t)(h * HDc + d) * 2;
    ko[idx] = in[src];
    vo[idx] = in[src + 1];
}

// ---------------------------------------------------------------------------
// Transpose bf16 [BH][R][128] -> [BH][128][R], 64x64 tiles
// ---------------------------------------------------------------------------
__global__ __launch_bounds__(256) void transpose_kernel(
    const ushort* __restrict__ in, ushort* __restrict__ out, int R)
{
    int bh = blockIdx.z;
    int r0 = blockIdx.x << 6, d0 = blockIdx.y << 6;
    const ushort* ip = in + (size_t)bh * R * HDc;
    ushort* op = out + (size_t)bh * HDc * R;
    __shared__ ushort tile[64][66];
    int t = threadIdx.x;
    int lr = t >> 5, lc = (t & 31) << 1;
    for (int rr = lr; rr < 64; rr += 8) {
        ushort2 v = *(const ushort2*)&ip[(size_t)(r0 + rr) * HDc + d0 + lc];
        tile[rr][lc] = v.x; tile[rr][lc + 1] = v.y;
    }
    __syncthreads();
    for (int dd = lr; dd < 64; dd += 8) {
        ushort2 v;
        v.x = tile[lc][dd]; v.y = tile[lc + 1][dd];
        *(ushort2*)&op[(size_t)(d0 + dd) * R + r0 + lc] = v;
    }
}

// ---------------------------------------------------------------------------
// MFMA flash attention v2 (bf16 in, fp32 softmax/accum, bf16 out).
// Computes S^T = K Q^T so softmax reduces in-lane (q = lane&15).
// Q,K: [BH][NQ/NK][128]; VT: [BH][128][NK]; O: [B][NQ][H*128] bf16
// 4 waves, q-tile 64 (16 q/wave: q = q0 + wave*16 + (lane&15)), key-tile 64.
// K/V/bias double-buffered; prefetch next key-tile before compute;
// ONE __syncthreads per key-tile.
// ---------------------------------------------------------------------------
__global__ __launch_bounds__(256) void attn_mfma_kernel(
    const ushort* __restrict__ Qg, const ushort* __restrict__ Kg,
    const ushort* __restrict__ VTg, ushort* __restrict__ O,
    int NQ, int NK, float scale_const, const float* __restrict__ scale_ptr,
    const float* __restrict__ bias_table, int causal)
{
    int qtiles = NQ >> 6;
    int qt = blockIdx.x % qtiles;
    int bh = blockIdx.x / qtiles;
    int h = bh % Hc, b = bh / Hc;
    int q0 = qt << 6;

    const ushort* Qb = Qg + (size_t)bh * NQ * HDc;
    const ushort* Kb = Kg + (size_t)bh * NK * HDc;
    const ushort* Vb = VTg + (size_t)bh * HDc * NK;

    float scale = scale_const * (scale_ptr ? scale_ptr[0] : 1.0f);

    __shared__ __align__(16) ushort Ks[2][16 * 512];   // 2 x 16KB: frag (mt,kt)
    __shared__ __align__(16) ushort Vs[2][16 * 512];   // 2 x 16KB: frag (dt,s)
    __shared__ __align__(16) ushort Ps[4][16][72];     // 9.2KB: P[q][key], per wave
    __shared__ float bias_s[2][128];

    int tid = threadIdx.x;
    int wave = tid >> 6, lane = tid & 63;
    int li = lane & 15, lq = lane >> 4;
    int qrel = (wave << 4) + li;   // this lane's query (rel to q0) in S^T/softmax

    // Q B-frags direct from global: B[n=q][k=d]: row q0+qrel, k=kt*32+lq*8
    bf16x8 qfrag[4];
    {
        const ushort* qrow = Qb + (size_t)(q0 + qrel) * HDc + (lq << 3);
#pragma unroll
        for (int kt = 0; kt < 4; ++kt)
            qfrag[kt] = *(const bf16x8*)&qrow[kt << 5];
    }

    f32x4 oacc[8];
#pragma unroll
    for (int i = 0; i < 8; ++i) { oacc[i][0] = 0.f; oacc[i][1] = 0.f; oacc[i][2] = 0.f; oacc[i][3] = 0.f; }
    float m_run = -INFINITY, l_run = 0.f;   // for q = qrel (replicated over lq)

    auto stage_kv = [&](int buf, int jt) {
        int j0 = jt << 6;
#pragma unroll
        for (int i = 0; i < 4; ++i) {
            int f = (wave << 2) + i;           // 0..15
            int mt = f >> 2, kt = f & 3;       // K: key-16-group, d-32-group
            const ushort* gk = Kb + (size_t)(j0 + (mt << 4) + li) * HDc + (kt << 5) + (lq << 3);
            gl2lds16(gk, &Ks[buf][f << 9]);
            int dt = f >> 1, s = f & 1;        // V: d-16-group, key-32-group
            const ushort* gv = Vb + (size_t)((dt << 4) + li) * NK + j0 + (s << 5) + (lq << 3);
            gl2lds16(gv, &Vs[buf][f << 9]);
        }
        if (bias_table && tid < 127)
            bias_s[buf][tid] = bias_table[(size_t)(j0 - q0 - 63 + Nc - 1 + tid) * Hc + h];
    };

    int jt_end = causal ? (q0 >> 6) + 1 : (NK >> 6);

    stage_kv(0, 0);
    __syncthreads();

    for (int jt = 0; jt < jt_end; ++jt) {
        int cur = jt & 1;
        if (jt + 1 < jt_end) stage_kv(cur ^ 1, jt + 1);
        int j0 = jt << 6;

        // ---- S^T = K Q^T : lane holds S[key=mt*16+lq*4+r][q=qrel] ----
        f32x4 sacc[4];
#pragma unroll
        for (int mt = 0; mt < 4; ++mt) {
            f32x4 s; s[0] = 0.f; s[1] = 0.f; s[2] = 0.f; s[3] = 0.f;
#pragma unroll
            for (int kt = 0; kt < 4; ++kt) {
                bf16x8 kf = *(const bf16x8*)&Ks[cur][(((mt << 2) + kt) << 9) + (lane << 3)];
                s = __builtin_amdgcn_mfma_f32_16x16x32_bf16(kf, qfrag[kt], s, 0, 0, 0);
            }
            sacc[mt] = s;
        }

        // ---- scale + bias + mask; in-lane tile max (query = qrel!) ----
        float sv[4][4];
        float mtile = -INFINITY;
#pragma unroll
        for (int mt = 0; mt < 4; ++mt)
#pragma unroll
            for (int r = 0; r < 4; ++r) {
                int jrel = (mt << 4) + (lq << 2) + r;
                float sx = sacc[mt][r] * scale;
                if (bias_table) sx += bias_s[cur][jrel - qrel + 63];
                if (causal && (j0 + jrel) > (q0 + qrel)) sx = -INFINITY;
                sv[mt][r] = sx;
                mtile = fmaxf(mtile, sx);
            }
        mtile = fmaxf(mtile, __shfl_xor(mtile, 16));
        mtile = fmaxf(mtile, __shfl_xor(mtile, 32));
        float m_new = fmaxf(m_run, mtile);
        float alpha = __expf(m_run - m_new);
        m_run = m_new;
        float ps = 0.f;
#pragma unroll
        for (int mt = 0; mt < 4; ++mt)
#pragma unroll
            for (int r = 0; r < 4; ++r) {
                float p = __expf(sv[mt][r] - m_new);
                sv[mt][r] = p;
                ps += p;
            }
        ps += __shfl_xor(ps, 16);
        ps += __shfl_xor(ps, 32);
        l_run = l_run * alpha + ps;

        // ---- write P[q=li][keys], 4x 8B packed stores (wave-private) ----
#pragma unroll
        for (int mt = 0; mt < 4; ++mt) {
            usx4 pk;
            pk.x = f2bf(sv[mt][0]); pk.y = f2bf(sv[mt][1]);
            pk.z = f2bf(sv[mt][2]); pk.w = f2bf(sv[mt][3]);
            *(usx4*)&Ps[wave][li][(mt << 4) + (lq << 2)] = pk;
        }

        // ---- rescale O by alpha(q = lq*4+r within wave) ----
        float ar[4];
#pragma unroll
        for (int r = 0; r < 4; ++r) ar[r] = __shfl(alpha, (lq << 2) + r);
#pragma unroll
        for (int dt = 0; dt < 8; ++dt)
#pragma unroll
            for (int r = 0; r < 4; ++r) oacc[dt][r] *= ar[r];

        // ---- O += P V : A=P-frag (own wave's Ps), B=V^T-frag ----
        bf16x8 pf0 = *(const bf16x8*)&Ps[wave][li][(lq << 3)];
        bf16x8 pf1 = *(const bf16x8*)&Ps[wave][li][32 + (lq << 3)];
#pragma unroll
        for (int dt = 0; dt < 8; ++dt) {
            bf16x8 v0 = *(const bf16x8*)&Vs[cur][(((dt << 1) + 0) << 9) + (lane << 3)];
            bf16x8 v1 = *(const bf16x8*)&Vs[cur][(((dt << 1) + 1) << 9) + (lane << 3)];
            oacc[dt] = __builtin_amdgcn_mfma_f32_16x16x32_bf16(pf0, v0, oacc[dt], 0, 0, 0);
            oacc[dt] = __builtin_amdgcn_mfma_f32_16x16x32_bf16(pf1, v1, oacc[dt], 0, 0, 0);
        }
        __syncthreads();   // prefetch landed; LDS reads of cur complete
    }

    // ---- epilogue: O /= l(q), write bf16 [B][NQ][H*128] ----
#pragma unroll
    for (int r = 0; r < 4; ++r) {
        float linv = 1.0f / __shfl(l_run, (lq << 2) + r);
        int gq = q0 + (wave << 4) + (lq << 2) + r;
        ushort* op = O + ((size_t)(b * NQ + gq)) * (Hc * HDc) + h * HDc;
#pragma unroll
        for (int dt = 0; dt < 8; ++dt)
            op[(dt << 4) + li] = f2bf(oacc[dt][r] * linv);
    }
}

// ---------------------------------------------------------------------------
// Host-side launch
// ---------------------------------------------------------------------------
static inline void launch_gemm(const ushort* A, const ushort* Bt, const float* bias,
                               const float* res, float* Cf, ushort* Cb,
                               int M_, int N_, int K_, int act, int ksplit,
                               hipStream_t s)
{
    dim3 g(N_ / 128, M_ / 128, ksplit);
    hipLaunchKernelGGL(gemm_bf16_kernel, g, dim3(256), 0, s,
                       A, Bt, bias, res, Cf, Cb, M_, N_, K_, act, ksplit);
}

extern "C" void kernel_launch(void* const* d_in, const int* in_sizes, int n_in,
                              void* d_out, int out_size, void* d_ws, size_t ws_size,
                              hipStream_t stream)
{
    const int*   tokens   = (const int*)  d_in[0];
    const float* acoustic = (const float*)d_in[1];
    const float* embed_w  = (const float*)d_in[2];
    const float* pe_freq  = (const float*)d_in[3];
    const float* pe_w     = (const float*)d_in[4];
    const float* pe_b     = (const float*)d_in[5];
    const float* dpb_w0   = (const float*)d_in[6];
    const float* dpb_b0   = (const float*)d_in[7];
    const float* dpb_w1   = (const float*)d_in[8];
    const float* dpb_b1   = (const float*)d_in[9];
    const float* dpb_w2   = (const float*)d_in[10];
    const float* dpb_b2   = (const float*)d_in[11];
    const float* ac_nw    = (const float*)d_in[12];
    const float* norm1    = (const float*)d_in[13];
    const float* norm2    = (const float*)d_in[14];
    const float* norm3    = (const float*)d_in[15];
    const float* sa_qkv   = (const float*)d_in[16];
    const float* sa_out_w = (const float*)d_in[17];
    const float* temp     = (const float*)d_in[18];
    const float* ca_q_w   = (const float*)d_in[19];
    const float* ca_kv_w  = (const float*)d_in[20];
    const float* ca_out_w = (const float*)d_in[21];
    const float* ff_w1    = (const float*)d_in[22];
    const float* ff_w2    = (const float*)d_in[23];
    const float* fin_nw   = (const float*)d_in[24];
    const float* out_w    = (const float*)d_in[25];
    const float* out_b    = (const float*)d_in[26];
    float* out = (float*)d_out;

    const size_t SZ_X   = (size_t)Bc * Nc * Dc;
    const size_t SZ_POS = (size_t)Nc * Dc;
    const size_t SZ_TAB = 16384;
    const size_t SZ_XKV = (size_t)Bc * Mc * Dc;
    const size_t SZ_BIG = (size_t)Bc * Nc * FFc;
    const size_t SZ_QH  = (size_t)Bc * Hc * Nc * HDc;
    const size_t SZ_KH  = (size_t)Bc * Hc * Mc * HDc;

    float* ws = (float*)d_ws;
    float* x     = ws;
    float* pos   = x + SZ_X;
    float* table = pos + SZ_POS;
    ushort* hx    = (ushort*)(table + SZ_TAB);
    ushort* xkvb  = hx + SZ_X;
    ushort* attnO = xkvb + SZ_XKV;
    ushort* bigBb = attnO + SZ_X;
    ushort* qb    = bigBb + SZ_BIG;
    ushort* kb    = qb + SZ_QH;
    ushort* vb    = kb + SZ_KH;
    ushort* vTb   = vb + SZ_KH;
    ushort* wT    = vTb + SZ_KH;

    const size_t W_QKV = (size_t)Dc * 3 * Hc * HDc;
    const size_t W_O   = (size_t)Hc * HDc * Dc;
    const size_t W_CKV = (size_t)Dc * 2 * Hc * HDc;
    const size_t W_F   = (size_t)Dc * FFc;
    const size_t W_LAYER = W_QKV + 3 * W_O + W_CKV + 2 * W_F;
    ushort* outWT = wT + 3 * W_LAYER;

    // Split-K partial buffers (reuse dead regions; all stream-ordered safe):
    //  Pq: 3 x [4096][768] fp32 = 9.44M floats over qb..vTb (11.0M floats free)
    //      used by sa_out / ca_out / ff2 when q/k/v/vT are dead.
    //  Pk: 2 x [4096][768] fp32 = 6.29M floats over kb..vb (exactly fits)
    //      used by ca_q (qb is being written by unpack at reduce time).
    float* Pq = (float*)qb;
    float* Pk = (float*)kb;
    const size_t MN = (size_t)Bc * Nc * Dc;

    const float CA_SCALE = 0.08838834764831843f; // 1/sqrt(128)

    // ---- weight transpose+convert ----
    for (int l = 0; l < Lc; ++l) {
        ushort* wl = wT + (size_t)l * W_LAYER;
        ushort* qkvT = wl;
        ushort* soT  = qkvT + W_QKV;
        ushort* cqT  = soT + W_O;
        ushort* ckvT = cqT + W_O;
        ushort* coT  = ckvT + W_CKV;
        ushort* f1T  = coT + W_O;
        ushort* f2T  = f1T + W_F;
        hipLaunchKernelGGL(wt_kernel, dim3(3 * Hc * HDc / 64, Dc / 64), dim3(256), 0, stream,
                           sa_qkv + (size_t)l * W_QKV, qkvT, Dc, 3 * Hc * HDc);
        hipLaunchKernelGGL(wt_kernel, dim3(Dc / 64, Hc * HDc / 64), dim3(256), 0, stream,
                           sa_out_w + (size_t)l * W_O, soT, Hc * HDc, Dc);
        hipLaunchKernelGGL(wt_kernel, dim3(Hc * HDc / 64, Dc / 64), dim3(256), 0, stream,
                           ca_q_w + (size_t)l * W_O, cqT, Dc, Hc * HDc);
        hipLaunchKernelGGL(wt_kernel, dim3(2 * Hc * HDc / 64, Dc / 64), dim3(256), 0, stream,
                           ca_kv_w + (size_t)l * W_CKV, ckvT, Dc, 2 * Hc * HDc);
        hipLaunchKernelGGL(wt_kernel, dim3(Dc / 64, Hc * HDc / 64), dim3(256), 0, stream,
                           ca_out_w + (size_t)l * W_O, coT, Hc * HDc, Dc);
        hipLaunchKernelGGL(wt_kernel, dim3(FFc / 64, Dc / 64), dim3(256), 0, stream,
                           ff_w1 + (size_t)l * W_F, f1T, Dc, FFc);
        hipLaunchKernelGGL(wt_kernel, dim3(Dc / 64, FFc / 64), dim3(256), 0, stream,
                           ff_w2 + (size_t)l * W_F, f2T, FFc, Dc);
    }
    hipLaunchKernelGGL(wt_kernel, dim3(Vc / 64, Dc / 64), dim3(256), 0, stream,
                       out_w, outWT, Dc, Vc);

    // ---- prologue ----
    hipLaunchKernelGGL(pos_pe_kernel, dim3(Nc), dim3(256), 0, stream,
                       pe_freq, pe_w, pe_b, pos);
    hipLaunchKernelGGL(embed_kernel, dim3((unsigned)((SZ_X + 255) / 256)), dim3(256), 0, stream,
                       tokens, embed_w, pos, x);
    hipLaunchKernelGGL(dpb_kernel, dim3(2 * Nc - 1), dim3(64), 0, stream,
                       dpb_w0, dpb_b0, dpb_w1, dpb_b1, dpb_w2, dpb_b2, table);
    hipLaunchKernelGGL(rms_kernel, dim3(Bc * Mc), dim3(256), 0, stream,
                       acoustic, ac_nw, xkvb);

    for (int l = 0; l < Lc; ++l) {
        const float* n1 = norm1 + (size_t)l * Dc;
        const float* n2 = norm2 + (size_t)l * Dc;
        const float* n3 = norm3 + (size_t)l * Dc;
        ushort* wl = wT + (size_t)l * W_LAYER;
        ushort* qkvT = wl;
        ushort* soT  = qkvT + W_QKV;
        ushort* cqT  = soT + W_O;
        ushort* ckvT = cqT + W_O;
        ushort* coT  = ckvT + W_CKV;
        ushort* f1T  = coT + W_O;
        ushort* f2T  = f1T + W_F;

        // --- self attention ---
        if (l == 0)
            hipLaunchKernelGGL(rms_kernel, dim3(Bc * Nc), dim3(256), 0, stream, x, n1, hx);
        else
            hipLaunchKernelGGL(rms_reduce_kernel, dim3(Bc * Nc), dim3(256), 0, stream,
                               x, Pq, 3, MN, n1, hx);   // fold prev layer's ff2
        launch_gemm(hx, qkvT, nullptr, nullptr, nullptr, bigBb,
                    Bc * Nc, 3 * Hc * HDc, Dc, 0, 1, stream);
        hipLaunchKernelGGL(unpack_sa_kernel, dim3(Bc * Nc * Hc), dim3(128), 0, stream,
                           bigBb, qb, kb, vb);
        hipLaunchKernelGGL(transpose_kernel, dim3(Nc / 64, 2, Bc * Hc), dim3(256), 0, stream,
                           vb, vTb, Nc);
        hipLaunchKernelGGL(attn_mfma_kernel, dim3(Bc * Hc * (Nc / 64)), dim3(256), 0, stream,
                           qb, kb, vTb, attnO, Nc, Nc, 1.0f, temp + l, table, 1);
        // x += attnO @ soT : split-K=3 partials (q/k/v/vT dead now)
        launch_gemm(attnO, soT, nullptr, nullptr, Pq, nullptr,
                    Bc * Nc, Dc, Hc * HDc, 0, 3, stream);
        hipLaunchKernelGGL(rms_reduce_kernel, dim3(Bc * Nc), dim3(256), 0, stream,
                           x, Pq, 3, MN, n2, hx);

        // --- cross attention ---
        launch_gemm(hx, cqT, nullptr, nullptr, Pk, nullptr,
                    Bc * Nc, Hc * HDc, Dc, 0, 2, stream);
        hipLaunchKernelGGL(unpack_caq_red_kernel, dim3((unsigned)((SZ_QH + 255) / 256)),
                           dim3(256), 0, stream, Pk, qb);
        launch_gemm(xkvb, ckvT, nullptr, nullptr, nullptr, bigBb,
                    Bc * Mc, 2 * Hc * HDc, Dc, 0, 1, stream);
        hipLaunchKernelGGL(unpack_cakv_kernel, dim3((unsigned)((SZ_KH + 255) / 256)), dim3(256),
                           0, stream, bigBb, kb, vb);
        hipLaunchKernelGGL(transpose_kernel, dim3(Mc / 64, 2, Bc * Hc), dim3(256), 0, stream,
                           vb, vTb, Mc);
        hipLaunchKernelGGL(attn_mfma_kernel, dim3(Bc * Hc * (Nc / 64)), dim3(256), 0, stream,
                           qb, kb, vTb, attnO, Nc, Mc, CA_SCALE, nullptr, nullptr, 0);
        // x += attnO @ coT : split-K=3 partials
        launch_gemm(attnO, coT, nullptr, nullptr, Pq, nullptr,
                    Bc * Nc, Dc, Hc * HDc, 0, 3, stream);
        hipLaunchKernelGGL(rms_reduce_kernel, dim3(Bc * Nc), dim3(256), 0, stream,
                           x, Pq, 3, MN, n3, hx);

        // --- feed-forward ---
        launch_gemm(hx, f1T, nullptr, nullptr, nullptr, bigBb,
                    Bc * Nc, FFc, Dc, 1, 1, stream);
        // x += bigBb @ f2T : split-K=3 partials (folded by next rms_reduce)
        launch_gemm(bigBb, f2T, nullptr, nullptr, Pq, nullptr,
                    Bc * Nc, Dc, FFc, 0, 3, stream);
    }

    // final norm (folds last ff2 partials) + logits
    hipLaunchKernelGGL(rms_reduce_kernel, dim3(Bc * Nc), dim3(256), 0, stream,
                       x, Pq, 3, MN, fin_nw, hx);
    launch_gemm(hx, outWT, out_b, nullptr, out, nullptr,
                Bc * Nc, Vc, Dc, 0, 1, stream);
}

// Round 4
// 1821.631 us; speedup vs baseline: 1.0505x; 1.0505x over previous
//
#include <hip/hip_runtime.h>
#include <hip/hip_bf16.h>
#include <math.h>
#include <stddef.h>

// Problem constants
#define Bc 4
#define Nc 1024
#define Mc 2048
#define Dc 768
#define Hc 6
#define HDc 128
#define Lc 3
#define Vc 4096
#define FFc 3072

typedef short bf16x8 __attribute__((ext_vector_type(8)));
typedef float f32x4 __attribute__((ext_vector_type(4)));
typedef ushort usx4 __attribute__((ext_vector_type(4)));

__device__ __forceinline__ float gelu_tanh(float x) {
    float x3 = x * x * x;
    return 0.5f * x * (1.0f + tanhf(0.7978845608028654f * (x + 0.044715f * x3)));
}
__device__ __forceinline__ float silu_f(float x) {
    return x / (1.0f + expf(-x));
}
// fp32 -> bf16 RNE, bit-level
__device__ __forceinline__ ushort f2bf(float x) {
    unsigned u = __float_as_uint(x);
    unsigned r = (u + 0x7fffu + ((u >> 16) & 1u)) >> 16;
    return (ushort)r;
}
__device__ __forceinline__ float bf2f(ushort u) {
    return __uint_as_float(((unsigned)u) << 16);
}
// async global->LDS 16B per lane; LDS dst = base + lane*16 (wave-uniform base)
__device__ __forceinline__ void gl2lds16(const ushort* g, ushort* l) {
    __builtin_amdgcn_global_load_lds(
        (const __attribute__((address_space(1))) unsigned int*)(g),
        (__attribute__((address_space(3))) unsigned int*)(l),
        16, 0, 0);
}
// bijective XCD swizzle: consecutive remapped ids stay on one XCD chunk
__device__ __forceinline__ int xcd_swz(int bid, int nwg) {
    int q = nwg >> 3, r = nwg & 7;
    int xcd = bid & 7, i = bid >> 3;
    return (xcd < r ? xcd * (q + 1) : r * (q + 1) + (xcd - r) * q) + i;
}

// ---------------------------------------------------------------------------
// Fourier positional encoding
// ---------------------------------------------------------------------------
__global__ __launch_bounds__(256) void pos_pe_kernel(
    const float* __restrict__ freq, const float* __restrict__ pe_w,
    const float* __restrict__ pe_b, float* __restrict__ pos)
{
    int n = blockIdx.x;
    __shared__ float feat[64];
    int tid = threadIdx.x;
    if (tid < 64) {
        float f;
        if (tid < 32) f = cosf((float)n * freq[tid]);
        else          f = sinf((float)n * freq[tid - 32]);
        feat[tid] = f * 0.125f;
    }
    __syncthreads();
    for (int d = tid; d < Dc; d += 256) {
        float s = pe_b[d];
#pragma unroll
        for (int h = 0; h < 64; ++h) s += feat[h] * pe_w[h * Dc + d];
        pos[(size_t)n * Dc + d] = s;
    }
}

__global__ __launch_bounds__(256) void embed_kernel(
    const int* __restrict__ tokens, const float* __restrict__ embed_w,
    const float* __restrict__ pos, float* __restrict__ x)
{
    size_t idx = (size_t)blockIdx.x * 256 + threadIdx.x;
    if (idx >= (size_t)Bc * Nc * Dc) return;
    int d  = (int)(idx % Dc);
    size_t bn = idx / Dc;
    int n  = (int)(bn % Nc);
    int tok = tokens[bn];
    x[idx] = embed_w[(size_t)tok * Dc + d] + pos[(size_t)n * Dc + d];
}

__global__ __launch_bounds__(64) void dpb_kernel(
    const float* __restrict__ w0, const float* __restrict__ b0,
    const float* __restrict__ w1, const float* __restrict__ b1,
    const float* __restrict__ w2, const float* __restrict__ b2,
    float* __restrict__ table)
{
    int r = blockIdx.x;
    int j = threadIdx.x;
    float dist = (float)r - (float)(Nc - 1);
    __shared__ float s0[64], s1[64];
    s0[j] = silu_f(dist * w0[j] + b0[j]);
    __syncthreads();
    float a = b1[j];
#pragma unroll 8
    for (int k = 0; k < 64; ++k) a += s0[k] * w1[k * 64 + j];
    s1[j] = silu_f(a);
    __syncthreads();
    if (j < Hc) {
        float t = b2[j];
#pragma unroll 8
        for (int k = 0; k < 64; ++k) t += s1[k] * w2[k * Hc + j];
        table[(size_t)r * Hc + j] = t;
    }
}

// RMSNorm fp32 in -> bf16 out. Dc=768=192*4: threads 0..191 do float4 lanes.
__global__ __launch_bounds__(256) void rms_kernel(
    const float* __restrict__ in, const float* __restrict__ w,
    ushort* __restrict__ out)
{
    size_t row = blockIdx.x;
    const float* rp = in + row * Dc;
    ushort* op = out + row * Dc;
    int tid = threadIdx.x;
    float4 v = make_float4(0.f, 0.f, 0.f, 0.f);
    float s = 0.f;
    int d4 = tid << 2;
    if (tid < 192) {
        v = *(const float4*)&rp[d4];
        s = v.x * v.x + v.y * v.y + v.z * v.z + v.w * v.w;
    }
    __shared__ float red[256];
    red[tid] = s;
    __syncthreads();
    for (int o = 128; o > 0; o >>= 1) {
        if (tid < o) red[tid] += red[tid + o];
        __syncthreads();
    }
    float rs = rsqrtf(red[0] * (1.0f / Dc) + 1e-8f);
    if (tid < 192) {
        float4 wv = *(const float4*)&w[d4];
        usx4 pk;
        pk.x = f2bf(v.x * rs * wv.x); pk.y = f2bf(v.y * rs * wv.y);
        pk.z = f2bf(v.z * rs * wv.z); pk.w = f2bf(v.w * rs * wv.w);
        *(usx4*)&op[d4] = pk;
    }
}

// ---------------------------------------------------------------------------
// Fused split-K reduce + residual update + RMSNorm:
//   x[row] += sum_z P[z][row];  out[row] = rms(x[row]) (bf16)
// Dc = 768 = 192*4; threads 0..191 each own one float4.
// ---------------------------------------------------------------------------
__global__ __launch_bounds__(256) void rms_reduce_kernel(
    float* __restrict__ x, const float* __restrict__ P, int nsplit, size_t MN,
    const float* __restrict__ w, ushort* __restrict__ out)
{
    size_t row = blockIdx.x;
    float* xp = x + row * Dc;
    ushort* op = out + row * Dc;
    int tid = threadIdx.x;
    int d4 = tid << 2;
    float4 v = make_float4(0.f, 0.f, 0.f, 0.f);
    float s = 0.f;
    if (tid < 192) {
        v = *(const float4*)&xp[d4];
        for (int z = 0; z < nsplit; ++z) {
            float4 p = *(const float4*)&P[(size_t)z * MN + row * Dc + d4];
            v.x += p.x; v.y += p.y; v.z += p.z; v.w += p.w;
        }
        *(float4*)&xp[d4] = v;
        s = v.x * v.x + v.y * v.y + v.z * v.z + v.w * v.w;
    }
    __shared__ float red[256];
    red[tid] = s;
    __syncthreads();
    for (int o = 128; o > 0; o >>= 1) {
        if (tid < o) red[tid] += red[tid + o];
        __syncthreads();
    }
    float rs = rsqrtf(red[0] * (1.0f / Dc) + 1e-8f);
    if (tid < 192) {
        float4 wv = *(const float4*)&w[d4];
        usx4 pk;
        pk.x = f2bf(v.x * rs * wv.x); pk.y = f2bf(v.y * rs * wv.y);
        pk.z = f2bf(v.z * rs * wv.z); pk.w = f2bf(v.w * rs * wv.w);
        *(usx4*)&op[d4] = pk;
    }
}

// ---------------------------------------------------------------------------
// Weight transpose+convert: in fp32 [K][N] -> out bf16 [N][K]. 64x64 tiles.
// ---------------------------------------------------------------------------
__global__ __launch_bounds__(256) void wt_kernel(
    const float* __restrict__ in, ushort* __restrict__ out, int K_, int N_)
{
    int n0 = blockIdx.x << 6, k0 = blockIdx.y << 6;
    __shared__ ushort t[64][65];
    int tid = threadIdx.x;
    int r = tid >> 4, c4 = (tid & 15) << 2;
    for (int rr = r; rr < 64; rr += 16) {
        float4 v = *(const float4*)&in[(size_t)(k0 + rr) * N_ + n0 + c4];
        t[rr][c4]     = f2bf(v.x);
        t[rr][c4 + 1] = f2bf(v.y);
        t[rr][c4 + 2] = f2bf(v.z);
        t[rr][c4 + 3] = f2bf(v.w);
    }
    __syncthreads();
    int nr = tid >> 2, cw = (tid & 3) << 4;
    ushort tmp[16];
#pragma unroll
    for (int j = 0; j < 16; ++j) tmp[j] = t[cw + j][nr];
#pragma unroll
    for (int s = 0; s < 2; ++s)
        *(bf16x8*)&out[(size_t)(n0 + nr) * K_ + k0 + cw + (s << 3)] =
            *(const bf16x8*)&tmp[s << 3];
}

// ---------------------------------------------------------------------------
// bf16 MFMA GEMM: C[M,N] = epi(A[M,K] @ Bt[N,K]^T)
// 128x128 tile, BK=32, 8 waves (512 thr, 2x4 of 64x32), frag-order LDS via
// global_load_lds. Double-buffered, prefetch next K-step, ONE barrier/K-step.
// acc[4][2] = 32 AGPR/wave -> ~2 blocks/CU = 16 waves/CU (2x round-3 TLP).
// Bijective XCD swizzle: same-XCD neighbors share the A-panel in L2.
// Split-K over blockIdx.z -> fp32 partial tiles at Cf + z*M*N.
// Epilogue staged through LDS; all global stores 16B/lane coalesced.
// ---------------------------------------------------------------------------
__global__ __launch_bounds__(512) void gemm_bf16_kernel(
    const ushort* __restrict__ A, const ushort* __restrict__ Bt,
    const float* __restrict__ bias, const float* __restrict__ res,
    float* __restrict__ Cf, ushort* __restrict__ Cb,
    int M_, int N_, int K_, int act, int ksplit)
{
    __shared__ __align__(16) ushort sraw[2 * 2 * 8 * 512];   // 32 KB total
    ushort* As = sraw;                 // [2][8*512]
    ushort* Bs = sraw + 2 * 8 * 512;   // [2][8*512]

    int nwg = gridDim.x * gridDim.y;
    int swz = xcd_swz(blockIdx.y * gridDim.x + blockIdx.x, nwg);
    int n0 = (swz % gridDim.x) << 7;
    int m0 = (swz / gridDim.x) << 7;

    int tid = threadIdx.x;
    int wave = tid >> 6, lane = tid & 63;
    int li = lane & 15, lq = lane >> 4;
    int wm = (wave >> 2) << 6;   // 0,64
    int wn = (wave & 3) << 5;    // 0,32,64,96

    int kchunk = K_ / ksplit;           // callers guarantee K_ % (32*ksplit)==0
    int kbeg = blockIdx.z * kchunk;
    int niter = kchunk >> 5;

    f32x4 acc[4][2];
#pragma unroll
    for (int i = 0; i < 4; ++i)
#pragma unroll
        for (int j = 0; j < 2; ++j) {
            acc[i][j][0] = 0.f; acc[i][j][1] = 0.f;
            acc[i][j][2] = 0.f; acc[i][j][3] = 0.f;
        }

    auto stage = [&](int buf, int k0) {
        // wave w stages A frag-block w (rows w*16..w*16+15) and B frag-block w
        const ushort* ga = A  + (size_t)(m0 + (wave << 4) + li) * K_ + k0 + (lq << 3);
        const ushort* gb = Bt + (size_t)(n0 + (wave << 4) + li) * K_ + k0 + (lq << 3);
        gl2lds16(ga, &As[(buf << 12) + (wave << 9)]);
        gl2lds16(gb, &Bs[(buf << 12) + (wave << 9)]);
    };

    stage(0, kbeg);
    __syncthreads();   // drains prologue loads (vmcnt 0)

    for (int it = 0; it < niter; ++it) {
        int cur = it & 1;
        if (it + 1 < niter) stage(cur ^ 1, kbeg + ((it + 1) << 5));
        bf16x8 af[4], bfr[2];
#pragma unroll
        for (int t = 0; t < 4; ++t)
            af[t]  = *(const bf16x8*)&As[(cur << 12) + (((wm >> 4) + t) << 9) + (lane << 3)];
#pragma unroll
        for (int t = 0; t < 2; ++t)
            bfr[t] = *(const bf16x8*)&Bs[(cur << 12) + (((wn >> 4) + t) << 9) + (lane << 3)];
#pragma unroll
        for (int mt = 0; mt < 4; ++mt)
#pragma unroll
            for (int nt = 0; nt < 2; ++nt)
                acc[mt][nt] = __builtin_amdgcn_mfma_f32_16x16x32_bf16(
                    af[mt], bfr[nt], acc[mt][nt], 0, 0, 0);
        __syncthreads();   // prefetch landed; LDS reads of cur complete
    }

    // ---- epilogue: stage tile through LDS, coalesced vector stores ----
    float* lt = (float*)sraw;   // 64 rows x 128 cols fp32 = 32 KB
    float* dstF = Cf;
    if (ksplit > 1) dstF = Cf + (size_t)blockIdx.z * M_ * N_;

#pragma unroll
    for (int half = 0; half < 2; ++half) {
        __syncthreads();
        if ((wm >> 6) == half) {
#pragma unroll
            for (int mt = 0; mt < 4; ++mt) {
#pragma unroll
                for (int r = 0; r < 4; ++r) {
                    int lrow = (mt << 4) + (lq << 2) + r;   // 0..63
                    int grow = m0 + (half << 6) + lrow;
#pragma unroll
                    for (int nt = 0; nt < 2; ++nt) {
                        int col = wn + (nt << 4) + li;
                        float v = acc[mt][nt][r];
                        if (ksplit == 1) {
                            int gcol = n0 + col;
                            if (bias) v += bias[gcol];
                            if (act == 1) v = gelu_tanh(v);
                            if (res) v += res[(size_t)grow * N_ + gcol];
                        }
                        lt[(lrow << 7) + col] = v;
                    }
                }
            }
        }
        __syncthreads();
        if (Cb) {
            // 2 passes x 32 rows; lane covers 8 cols -> 16B bf16 store
            int lrow = tid >> 4;            // 0..31
            int c8 = (tid & 15) << 3;       // 0..120
#pragma unroll
            for (int p = 0; p < 2; ++p) {
                int row = (p << 5) + lrow;
                f32x4 a = *(const f32x4*)&lt[(row << 7) + c8];
                f32x4 b = *(const f32x4*)&lt[(row << 7) + c8 + 4];
                union { bf16x8 v; ushort u[8]; } pk;
#pragma unroll
                for (int j = 0; j < 4; ++j) {
                    pk.u[j] = f2bf(a[j]);
                    pk.u[4 + j] = f2bf(b[j]);
                }
                int grow = m0 + (half << 6) + row;
                *(bf16x8*)&Cb[(size_t)grow * N_ + n0 + c8] = pk.v;
            }
        } else {
            // 4 passes x 16 rows; lane covers 4 cols -> 16B fp32 store
            int lrow = tid >> 5;            // 0..15
            int c4 = (tid & 31) << 2;       // 0..124
#pragma unroll
            for (int p = 0; p < 4; ++p) {
                int row = (p << 4) + lrow;
                f32x4 a = *(const f32x4*)&lt[(row << 7) + c4];
                int grow = m0 + (half << 6) + row;
                *(f32x4*)&dstF[(size_t)grow * N_ + n0 + c4] = a;
            }
        }
    }
}

// ---------------------------------------------------------------------------
// Unpack SA qkv (bf16) -> bf16 q,k (l2-normalized), v [BH][N][128]
// ---------------------------------------------------------------------------
__global__ __launch_bounds__(128) void unpack_sa_kernel(
    const ushort* __restrict__ qkv, ushort* __restrict__ qo,
    ushort* __restrict__ ko, ushort* __restrict__ vo)
{
    int bid = blockIdx.x;
    int h = bid % Hc;
    int bn = bid / Hc;
    int b = bn / Nc, n = bn % Nc;
    int d = threadIdx.x;
    size_t base = (size_t)bn * (3 * Hc * HDc) + (size_t)(h * HDc + d) * 3;
    float q = bf2f(qkv[base]), k = bf2f(qkv[base + 1]);
    ushort v = qkv[base + 2];
    __shared__ float rq[128], rk[128];
    rq[d] = q * q; rk[d] = k * k;
    __syncthreads();
    for (int o = 64; o > 0; o >>= 1) {
        if (d < o) { rq[d] += rq[d + o]; rk[d] += rk[d + o]; }
        __syncthreads();
    }
    float qn = fmaxf(sqrtf(rq[0]), 1e-12f);
    float kn = fmaxf(sqrtf(rk[0]), 1e-12f);
    size_t oidx = (((size_t)(b * Hc + h) * Nc) + n) * HDc + d;
    qo[oidx] = f2bf(q / qn);
    ko[oidx] = f2bf(k / kn);
    vo[oidx] = v;
}

// ---------------------------------------------------------------------------
// Unpack CA q from 2 fp32 split-K partials: sum -> bf16 [BH][N][128]
// ---------------------------------------------------------------------------
__global__ __launch_bounds__(256) void unpack_caq_red_kernel(
    const float* __restrict__ P, ushort* __restrict__ qo)
{
    size_t idx = (size_t)blockIdx.x * 256 + threadIdx.x;
    if (idx >= (size_t)Bc * Hc * Nc * HDc) return;
    int d = (int)(idx & (HDc - 1));
    size_t t = idx >> 7;
    int n = (int)(t % Nc); t /= Nc;
    int h = (int)(t % Hc); int b = (int)(t / Hc);
    const size_t MNq = (size_t)Bc * Nc * (Hc * HDc);
    size_t src = ((size_t)(b * Nc + n)) * (Hc * HDc) + h * HDc + d;
    qo[idx] = f2bf(P[src] + P[MNq + src]);
}

// ---------------------------------------------------------------------------
// Unpack CA kv: bf16 [B*M][(h*128+d)*2+c] -> bf16 k,v [BH][M][128]
// ---------------------------------------------------------------------------
__global__ __launch_bounds__(256) void unpack_cakv_kernel(
    const ushort* __restrict__ in, ushort* __restrict__ ko, ushort* __restrict__ vo)
{
    size_t idx = (size_t)blockIdx.x * 256 + threadIdx.x;
    if (idx >= (size_t)Bc * Hc * Mc * HDc) return;
    int d = (int)(idx & (HDc - 1));
    size_t t = idx >> 7;
    int m = (int)(t % Mc); t /= Mc;
    int h = (int)(t % Hc); int b = (int)(t / Hc);
    size_t src = ((size_t)(b * Mc + m)) * (2 * Hc * HDc) + (size_t)(h * HDc + d) * 2;
    ko[idx] = in[src];
    vo[idx] = in[src + 1];
}

// ---------------------------------------------------------------------------
// Transpose bf16 [BH][R][128] -> [BH][128][R], 64x64 tiles
// ---------------------------------------------------------------------------
__global__ __launch_bounds__(256) void transpose_kernel(
    const ushort* __restrict__ in, ushort* __restrict__ out, int R)
{
    int bh = blockIdx.z;
    int r0 = blockIdx.x << 6, d0 = blockIdx.y << 6;
    const ushort* ip = in + (size_t)bh * R * HDc;
    ushort* op = out + (size_t)bh * HDc * R;
    __shared__ ushort tile[64][66];
    int t = threadIdx.x;
    int lr = t >> 5, lc = (t & 31) << 1;
    for (int rr = lr; rr < 64; rr += 8) {
        ushort2 v = *(const ushort2*)&ip[(size_t)(r0 + rr) * HDc + d0 + lc];
        tile[rr][lc] = v.x; tile[rr][lc + 1] = v.y;
    }
    __syncthreads();
    for (int dd = lr; dd < 64; dd += 8) {
        ushort2 v;
        v.x = tile[lc][dd]; v.y = tile[lc + 1][dd];
        *(ushort2*)&op[(size_t)(d0 + dd) * R + r0 + lc] = v;
    }
}

// ---------------------------------------------------------------------------
// MFMA flash attention v2 (bf16 in, fp32 softmax/accum, bf16 out).
// Computes S^T = K Q^T so softmax reduces in-lane (q = lane&15).
// Q,K: [BH][NQ/NK][128]; VT: [BH][128][NK]; O: [B][NQ][H*128] bf16
// 4 waves, q-tile 64, key-tile 64; K/V/bias double-buffered, one barrier
// per key-tile. XCD swizzle keeps same-head blocks (sharing K/V) on one XCD.
// ---------------------------------------------------------------------------
__global__ __launch_bounds__(256) void attn_mfma_kernel(
    const ushort* __restrict__ Qg, const ushort* __restrict__ Kg,
    const ushort* __restrict__ VTg, ushort* __restrict__ O,
    int NQ, int NK, float scale_const, const float* __restrict__ scale_ptr,
    const float* __restrict__ bias_table, int causal)
{
    int qtiles = NQ >> 6;
    int bid = xcd_swz(blockIdx.x, gridDim.x);
    int qt = bid % qtiles;
    int bh = bid / qtiles;
    int h = bh % Hc, b = bh / Hc;
    int q0 = qt << 6;

    const ushort* Qb = Qg + (size_t)bh * NQ * HDc;
    const ushort* Kb = Kg + (size_t)bh * NK * HDc;
    const ushort* Vb = VTg + (size_t)bh * HDc * NK;

    float scale = scale_const * (scale_ptr ? scale_ptr[0] : 1.0f);

    __shared__ __align__(16) ushort Ks[2][16 * 512];   // 2 x 16KB: frag (mt,kt)
    __shared__ __align__(16) ushort Vs[2][16 * 512];   // 2 x 16KB: frag (dt,s)
    __shared__ __align__(16) ushort Ps[4][16][72];     // 9.2KB: P[q][key], per wave
    __shared__ float bias_s[2][128];

    int tid = threadIdx.x;
    int wave = tid >> 6, lane = tid & 63;
    int li = lane & 15, lq = lane >> 4;
    int qrel = (wave << 4) + li;   // this lane's query (rel to q0) in S^T/softmax

    // Q B-frags direct from global: B[n=q][k=d]: row q0+qrel, k=kt*32+lq*8
    bf16x8 qfrag[4];
    {
        const ushort* qrow = Qb + (size_t)(q0 + qrel) * HDc + (lq << 3);
#pragma unroll
        for (int kt = 0; kt < 4; ++kt)
            qfrag[kt] = *(const bf16x8*)&qrow[kt << 5];
    }

    f32x4 oacc[8];
#pragma unroll
    for (int i = 0; i < 8; ++i) { oacc[i][0] = 0.f; oacc[i][1] = 0.f; oacc[i][2] = 0.f; oacc[i][3] = 0.f; }
    float m_run = -INFINITY, l_run = 0.f;   // for q = qrel (replicated over lq)

    auto stage_kv = [&](int buf, int jt) {
        int j0 = jt << 6;
#pragma unroll
        for (int i = 0; i < 4; ++i) {
            int f = (wave << 2) + i;           // 0..15
            int mt = f >> 2, kt = f & 3;       // K: key-16-group, d-32-group
            const ushort* gk = Kb + (size_t)(j0 + (mt << 4) + li) * HDc + (kt << 5) + (lq << 3);
            gl2lds16(gk, &Ks[buf][f << 9]);
            int dt = f >> 1, s = f & 1;        // V: d-16-group, key-32-group
            const ushort* gv = Vb + (size_t)((dt << 4) + li) * NK + j0 + (s << 5) + (lq << 3);
            gl2lds16(gv, &Vs[buf][f << 9]);
        }
        if (bias_table && tid < 127)
            bias_s[buf][tid] = bias_table[(size_t)(j0 - q0 - 63 + Nc - 1 + tid) * Hc + h];
    };

    int jt_end = causal ? (q0 >> 6) + 1 : (NK >> 6);

    stage_kv(0, 0);
    __syncthreads();

    for (int jt = 0; jt < jt_end; ++jt) {
        int cur = jt & 1;
        if (jt + 1 < jt_end) stage_kv(cur ^ 1, jt + 1);
        int j0 = jt << 6;

        // ---- S^T = K Q^T : lane holds S[key=mt*16+lq*4+r][q=qrel] ----
        f32x4 sacc[4];
#pragma unroll
        for (int mt = 0; mt < 4; ++mt) {
            f32x4 s; s[0] = 0.f; s[1] = 0.f; s[2] = 0.f; s[3] = 0.f;
#pragma unroll
            for (int kt = 0; kt < 4; ++kt) {
                bf16x8 kf = *(const bf16x8*)&Ks[cur][(((mt << 2) + kt) << 9) + (lane << 3)];
                s = __builtin_amdgcn_mfma_f32_16x16x32_bf16(kf, qfrag[kt], s, 0, 0, 0);
            }
            sacc[mt] = s;
        }

        // ---- scale + bias + mask; in-lane tile max (query = qrel!) ----
        float sv[4][4];
        float mtile = -INFINITY;
#pragma unroll
        for (int mt = 0; mt < 4; ++mt)
#pragma unroll
            for (int r = 0; r < 4; ++r) {
                int jrel = (mt << 4) + (lq << 2) + r;
                float sx = sacc[mt][r] * scale;
                if (bias_table) sx += bias_s[cur][jrel - qrel + 63];
                if (causal && (j0 + jrel) > (q0 + qrel)) sx = -INFINITY;
                sv[mt][r] = sx;
                mtile = fmaxf(mtile, sx);
            }
        mtile = fmaxf(mtile, __shfl_xor(mtile, 16));
        mtile = fmaxf(mtile, __shfl_xor(mtile, 32));
        float m_new = fmaxf(m_run, mtile);
        float alpha = __expf(m_run - m_new);
        m_run = m_new;
        float ps = 0.f;
#pragma unroll
        for (int mt = 0; mt < 4; ++mt)
#pragma unroll
            for (int r = 0; r < 4; ++r) {
                float p = __expf(sv[mt][r] - m_new);
                sv[mt][r] = p;
                ps += p;
            }
        ps += __shfl_xor(ps, 16);
        ps += __shfl_xor(ps, 32);
        l_run = l_run * alpha + ps;

        // ---- write P[q=li][keys], 4x 8B packed stores (wave-private) ----
#pragma unroll
        for (int mt = 0; mt < 4; ++mt) {
            usx4 pk;
            pk.x = f2bf(sv[mt][0]); pk.y = f2bf(sv[mt][1]);
            pk.z = f2bf(sv[mt][2]); pk.w = f2bf(sv[mt][3]);
            *(usx4*)&Ps[wave][li][(mt << 4) + (lq << 2)] = pk;
        }

        // ---- rescale O by alpha(q = lq*4+r within wave) ----
        float ar[4];
#pragma unroll
        for (int r = 0; r < 4; ++r) ar[r] = __shfl(alpha, (lq << 2) + r);
#pragma unroll
        for (int dt = 0; dt < 8; ++dt)
#pragma unroll
            for (int r = 0; r < 4; ++r) oacc[dt][r] *= ar[r];

        // ---- O += P V : A=P-frag (own wave's Ps), B=V^T-frag ----
        bf16x8 pf0 = *(const bf16x8*)&Ps[wave][li][(lq << 3)];
        bf16x8 pf1 = *(const bf16x8*)&Ps[wave][li][32 + (lq << 3)];
#pragma unroll
        for (int dt = 0; dt < 8; ++dt) {
            bf16x8 v0 = *(const bf16x8*)&Vs[cur][(((dt << 1) + 0) << 9) + (lane << 3)];
            bf16x8 v1 = *(const bf16x8*)&Vs[cur][(((dt << 1) + 1) << 9) + (lane << 3)];
            oacc[dt] = __builtin_amdgcn_mfma_f32_16x16x32_bf16(pf0, v0, oacc[dt], 0, 0, 0);
            oacc[dt] = __builtin_amdgcn_mfma_f32_16x16x32_bf16(pf1, v1, oacc[dt], 0, 0, 0);
        }
        __syncthreads();   // prefetch landed; LDS reads of cur complete
    }

    // ---- epilogue: O /= l(q), write bf16 [B][NQ][H*128] ----
#pragma unroll
    for (int r = 0; r < 4; ++r) {
        float linv = 1.0f / __shfl(l_run, (lq << 2) + r);
        int gq = q0 + (wave << 4) + (lq << 2) + r;
        ushort* op = O + ((size_t)(b * NQ + gq)) * (Hc * HDc) + h * HDc;
#pragma unroll
        for (int dt = 0; dt < 8; ++dt)
            op[(dt << 4) + li] = f2bf(oacc[dt][r] * linv);
    }
}

// ---------------------------------------------------------------------------
// Host-side launch
// ---------------------------------------------------------------------------
static inline void launch_gemm(const ushort* A, const ushort* Bt, const float* bias,
                               const float* res, float* Cf, ushort* Cb,
                               int M_, int N_, int K_, int act, int ksplit,
                               hipStream_t s)
{
    dim3 g(N_ / 128, M_ / 128, ksplit);
    hipLaunchKernelGGL(gemm_bf16_kernel, g, dim3(512), 0, s,
                       A, Bt, bias, res, Cf, Cb, M_, N_, K_, act, ksplit);
}

extern "C" void kernel_launch(void* const* d_in, const int* in_sizes, int n_in,
                              void* d_out, int out_size, void* d_ws, size_t ws_size,
                              hipStream_t stream)
{
    const int*   tokens   = (const int*)  d_in[0];
    const float* acoustic = (const float*)d_in[1];
    const float* embed_w  = (const float*)d_in[2];
    const float* pe_freq  = (const float*)d_in[3];
    const float* pe_w     = (const float*)d_in[4];
    const float* pe_b     = (const float*)d_in[5];
    const float* dpb_w0   = (const float*)d_in[6];
    const float* dpb_b0   = (const float*)d_in[7];
    const float* dpb_w1   = (const float*)d_in[8];
    const float* dpb_b1   = (const float*)d_in[9];
    const float* dpb_w2   = (const float*)d_in[10];
    const float* dpb_b2   = (const float*)d_in[11];
    const float* ac_nw    = (const float*)d_in[12];
    const float* norm1    = (const float*)d_in[13];
    const float* norm2    = (const float*)d_in[14];
    const float* norm3    = (const float*)d_in[15];
    const float* sa_qkv   = (const float*)d_in[16];
    const float* sa_out_w = (const float*)d_in[17];
    const float* temp     = (const float*)d_in[18];
    const float* ca_q_w   = (const float*)d_in[19];
    const float* ca_kv_w  = (const float*)d_in[20];
    const float* ca_out_w = (const float*)d_in[21];
    const float* ff_w1    = (const float*)d_in[22];
    const float* ff_w2    = (const float*)d_in[23];
    const float* fin_nw   = (const float*)d_in[24];
    const float* out_w    = (const float*)d_in[25];
    const float* out_b    = (const float*)d_in[26];
    float* out = (float*)d_out;

    const size_t SZ_X   = (size_t)Bc * Nc * Dc;
    const size_t SZ_POS = (size_t)Nc * Dc;
    const size_t SZ_TAB = 16384;
    const size_t SZ_XKV = (size_t)Bc * Mc * Dc;
    const size_t SZ_BIG = (size_t)Bc * Nc * FFc;
    const size_t SZ_QH  = (size_t)Bc * Hc * Nc * HDc;
    const size_t SZ_KH  = (size_t)Bc * Hc * Mc * HDc;

    float* ws = (float*)d_ws;
    float* x     = ws;
    float* pos   = x + SZ_X;
    float* table = pos + SZ_POS;
    ushort* hx    = (ushort*)(table + SZ_TAB);
    ushort* xkvb  = hx + SZ_X;
    ushort* attnO = xkvb + SZ_XKV;
    ushort* bigBb = attnO + SZ_X;
    ushort* qb    = bigBb + SZ_BIG;
    ushort* kb    = qb + SZ_QH;
    ushort* vb    = kb + SZ_KH;
    ushort* vTb   = vb + SZ_KH;
    ushort* wT    = vTb + SZ_KH;

    const size_t W_QKV = (size_t)Dc * 3 * Hc * HDc;
    const size_t W_O   = (size_t)Hc * HDc * Dc;
    const size_t W_CKV = (size_t)Dc * 2 * Hc * HDc;
    const size_t W_F   = (size_t)Dc * FFc;
    const size_t W_LAYER = W_QKV + 3 * W_O + W_CKV + 2 * W_F;
    ushort* outWT = wT + 3 * W_LAYER;

    // Split-K partial buffers (reuse dead regions; all stream-ordered safe):
    //  Pq: 3 x [4096][768] fp32 over qb..vTb (q/k/v/vT dead at those points)
    //  Pk: 2 x [4096][768] fp32 over kb..vb (ca_q partials)
    float* Pq = (float*)qb;
    float* Pk = (float*)kb;
    const size_t MN = (size_t)Bc * Nc * Dc;

    const float CA_SCALE = 0.08838834764831843f; // 1/sqrt(128)

    // ---- weight transpose+convert ----
    for (int l = 0; l < Lc; ++l) {
        ushort* wl = wT + (size_t)l * W_LAYER;
        ushort* qkvT = wl;
        ushort* soT  = qkvT + W_QKV;
        ushort* cqT  = soT + W_O;
        ushort* ckvT = cqT + W_O;
        ushort* coT  = ckvT + W_CKV;
        ushort* f1T  = coT + W_O;
        ushort* f2T  = f1T + W_F;
        hipLaunchKernelGGL(wt_kernel, dim3(3 * Hc * HDc / 64, Dc / 64), dim3(256), 0, stream,
                           sa_qkv + (size_t)l * W_QKV, qkvT, Dc, 3 * Hc * HDc);
        hipLaunchKernelGGL(wt_kernel, dim3(Dc / 64, Hc * HDc / 64), dim3(256), 0, stream,
                           sa_out_w + (size_t)l * W_O, soT, Hc * HDc, Dc);
        hipLaunchKernelGGL(wt_kernel, dim3(Hc * HDc / 64, Dc / 64), dim3(256), 0, stream,
                           ca_q_w + (size_t)l * W_O, cqT, Dc, Hc * HDc);
        hipLaunchKernelGGL(wt_kernel, dim3(2 * Hc * HDc / 64, Dc / 64), dim3(256), 0, stream,
                           ca_kv_w + (size_t)l * W_CKV, ckvT, Dc, 2 * Hc * HDc);
        hipLaunchKernelGGL(wt_kernel, dim3(Dc / 64, Hc * HDc / 64), dim3(256), 0, stream,
                           ca_out_w + (size_t)l * W_O, coT, Hc * HDc, Dc);
        hipLaunchKernelGGL(wt_kernel, dim3(FFc / 64, Dc / 64), dim3(256), 0, stream,
                           ff_w1 + (size_t)l * W_F, f1T, Dc, FFc);
        hipLaunchKernelGGL(wt_kernel, dim3(Dc / 64, FFc / 64), dim3(256), 0, stream,
                           ff_w2 + (size_t)l * W_F, f2T, FFc, Dc);
    }
    hipLaunchKernelGGL(wt_kernel, dim3(Vc / 64, Dc / 64), dim3(256), 0, stream,
                       out_w, outWT, Dc, Vc);

    // ---- prologue ----
    hipLaunchKernelGGL(pos_pe_kernel, dim3(Nc), dim3(256), 0, stream,
                       pe_freq, pe_w, pe_b, pos);
    hipLaunchKernelGGL(embed_kernel, dim3((unsigned)((SZ_X + 255) / 256)), dim3(256), 0, stream,
                       tokens, embed_w, pos, x);
    hipLaunchKernelGGL(dpb_kernel, dim3(2 * Nc - 1), dim3(64), 0, stream,
                       dpb_w0, dpb_b0, dpb_w1, dpb_b1, dpb_w2, dpb_b2, table);
    hipLaunchKernelGGL(rms_kernel, dim3(Bc * Mc), dim3(256), 0, stream,
                       acoustic, ac_nw, xkvb);

    for (int l = 0; l < Lc; ++l) {
        const float* n1 = norm1 + (size_t)l * Dc;
        const float* n2 = norm2 + (size_t)l * Dc;
        const float* n3 = norm3 + (size_t)l * Dc;
        ushort* wl = wT + (size_t)l * W_LAYER;
        ushort* qkvT = wl;
        ushort* soT  = qkvT + W_QKV;
        ushort* cqT  = soT + W_O;
        ushort* ckvT = cqT + W_O;
        ushort* coT  = ckvT + W_CKV;
        ushort* f1T  = coT + W_O;
        ushort* f2T  = f1T + W_F;

        // --- self attention ---
        if (l == 0)
            hipLaunchKernelGGL(rms_kernel, dim3(Bc * Nc), dim3(256), 0, stream, x, n1, hx);
        else
            hipLaunchKernelGGL(rms_reduce_kernel, dim3(Bc * Nc), dim3(256), 0, stream,
                               x, Pq, 3, MN, n1, hx);   // fold prev layer's ff2
        launch_gemm(hx, qkvT, nullptr, nullptr, nullptr, bigBb,
                    Bc * Nc, 3 * Hc * HDc, Dc, 0, 1, stream);
        hipLaunchKernelGGL(unpack_sa_kernel, dim3(Bc * Nc * Hc), dim3(128), 0, stream,
                           bigBb, qb, kb, vb);
        hipLaunchKernelGGL(transpose_kernel, dim3(Nc / 64, 2, Bc * Hc), dim3(256), 0, stream,
                           vb, vTb, Nc);
        hipLaunchKernelGGL(attn_mfma_kernel, dim3(Bc * Hc * (Nc / 64)), dim3(256), 0, stream,
                           qb, kb, vTb, attnO, Nc, Nc, 1.0f, temp + l, table, 1);
        // x += attnO @ soT : split-K=3 partials (q/k/v/vT dead now)
        launch_gemm(attnO, soT, nullptr, nullptr, Pq, nullptr,
                    Bc * Nc, Dc, Hc * HDc, 0, 3, stream);
        hipLaunchKernelGGL(rms_reduce_kernel, dim3(Bc * Nc), dim3(256), 0, stream,
                           x, Pq, 3, MN, n2, hx);

        // --- cross attention ---
        launch_gemm(hx, cqT, nullptr, nullptr, Pk, nullptr,
                    Bc * Nc, Hc * HDc, Dc, 0, 2, stream);
        hipLaunchKernelGGL(unpack_caq_red_kernel, dim3((unsigned)((SZ_QH + 255) / 256)),
                           dim3(256), 0, stream, Pk, qb);
        launch_gemm(xkvb, ckvT, nullptr, nullptr, nullptr, bigBb,
                    Bc * Mc, 2 * Hc * HDc, Dc, 0, 1, stream);
        hipLaunchKernelGGL(unpack_cakv_kernel, dim3((unsigned)((SZ_KH + 255) / 256)), dim3(256),
                           0, stream, bigBb, kb, vb);
        hipLaunchKernelGGL(transpose_kernel, dim3(Mc / 64, 2, Bc * Hc), dim3(256), 0, stream,
                           vb, vTb, Mc);
        hipLaunchKernelGGL(attn_mfma_kernel, dim3(Bc * Hc * (Nc / 64)), dim3(256), 0, stream,
                           qb, kb, vTb, attnO, Nc, Mc, CA_SCALE, nullptr, nullptr, 0);
        // x += attnO @ coT : split-K=3 partials
        launch_gemm(attnO, coT, nullptr, nullptr, Pq, nullptr,
                    Bc * Nc, Dc, Hc * HDc, 0, 3, stream);
        hipLaunchKernelGGL(rms_reduce_kernel, dim3(Bc * Nc), dim3(256), 0, stream,
                           x, Pq, 3, MN, n3, hx);

        // --- feed-forward ---
        launch_gemm(hx, f1T, nullptr, nullptr, nullptr, bigBb,
                    Bc * Nc, FFc, Dc, 1, 1, stream);
        // x += bigBb @ f2T : split-K=3 partials (folded by next rms_reduce)
        launch_gemm(bigBb, f2T, nullptr, nullptr, Pq, nullptr,
                    Bc * Nc, Dc, FFc, 0, 3, stream);
    }

    // final norm (folds last ff2 partials) + logits
    hipLaunchKernelGGL(rms_reduce_kernel, dim3(Bc * Nc), dim3(256), 0, stream,
                       x, Pq, 3, MN, fin_nw, hx);
    launch_gemm(hx, outWT, out_b, nullptr, out, nullptr,
                Bc * Nc, Vc, Dc, 0, 1, stream);
}